// Round 1
// baseline (133.023 us; speedup 1.0000x reference)
//
#include <hip/hip_runtime.h>

// Quantum circuit sim: 16 qubits, 2 layers of (RX,RY,RZ per qubit + CNOT ring), batch 32.
// Circuit = P * R1 * P * R0  where R* = 16 single-qubit 2x2 gates, P = CNOT-ring permutation.
// Reference reshape is row-major: qubit q <-> bit (15-q) of the flat index.
// P as index gather: psi'[i] = psi[f(i)],  f(i) = i ^ (i>>1) ^ (bit0(i)?0xC000:0).
// f^{-1}(j): suffix-xor cascade; bit15 = parity(j & 0x7FFF).
// Conjugated gate P^{-1} G_b P: pair mask f(e_b), selector parity(i & (0xFFFF<<b)) (b<=14; b=15 -> 0x7FFF).
//
// Pass 1: local bits 0..12   -> layer-0 gates on bits 0..12
// Pass 2: local {0..9,13..15}-> layer-0 on 13..15, then layer-1 (conjugated) on b in {0,1..9,14,15}
// Pass 3: local j-bits {0..8,10..13} -> gather B[f(j)], layer-1 standard on bits 10..13,
//         out[f^{-1}(j)] = |amp|^2  (f^{-1} lower-triangular => wave-coalesced 256B scatter windows)

#define NT 512
#define NLOC 8192   // 2^13 amps per block
#define NPAIR 4096

__device__ __forceinline__ int fperm(int x) {
  int y = x ^ (x >> 1);
  y ^= (x & 1) ? 0xC000 : 0;
  return y & 0xFFFF;
}

__device__ __forceinline__ int finv16(int x) {
  int s = x;
  s ^= s >> 1; s ^= s >> 2; s ^= s >> 4; s ^= s >> 8;   // s_t = parity of bits >= t
  int b15 = ((s ^ (s >> 15)) & 1) << 15;                // o15 = parity(x & 0x7FFF)
  return (s & 0x7FFF) | b15;
}

// ---- gate table prelude: U^{(l)}_q = RZ*RY*RX, 32 gates x 8 floats into gbuf ----
__global__ void gates_k(const float* __restrict__ th, float* __restrict__ gbuf) {
  int tid = threadIdx.x;
  if (tid < 32) {
    int l = tid >> 4, q = tid & 15;
    float tx = th[l * 48 + q], ty = th[l * 48 + 16 + q], tz = th[l * 48 + 32 + q];
    float cx, sx, cy, sy, cz, sz;
    sincosf(0.5f * tx, &sx, &cx);
    sincosf(0.5f * ty, &sy, &cy);
    sincosf(0.5f * tz, &sz, &cz);
    // M = RY*RX
    float m00r = cy * cx, m00i =  sy * sx;
    float m01r = -sy * cx, m01i = -cy * sx;
    float m10r =  sy * cx, m10i = -cy * sx;
    float m11r =  cy * cx, m11i = -sy * sx;
    float* G = gbuf + tid * 8;
    // row0 *= e^{-i tz/2}, row1 *= e^{+i tz/2}
    G[0] = cz * m00r + sz * m00i;  G[1] = cz * m00i - sz * m00r;
    G[2] = cz * m01r + sz * m01i;  G[3] = cz * m01i - sz * m01r;
    G[4] = cz * m10r - sz * m10i;  G[5] = cz * m10i + sz * m10r;
    G[6] = cz * m11r - sz * m11i;  G[7] = cz * m11i + sz * m11r;
  }
}

// ---- local-index -> full 16-bit amp-index maps ----
struct Map1 { int hb;  __device__ int operator()(int l) const { return hb | l; } };
struct Map2 { int mb;  __device__ int operator()(int l) const { return (l & 1023) | mb | ((l >> 10) << 13); } };
struct Map3 { int gb;  __device__ int operator()(int l) const { return (l & 511) | ((l >> 9) << 10) | gb; } };

// Generic butterfly: pairs (i0, i0^Ml) with pivot = lowest bit of Ml; selector row =
// parity(fullindex(i0) & selmask). Two-phase (read-all, barrier, write-all) for LDS ILP.
template <typename IMAP>
__device__ __forceinline__ void apply_gate(float* sre, float* sim,
                                           const float* __restrict__ G,
                                           int Ml, int selmask, IMAP imap) {
  float g0 = G[0], g1 = G[1], g2 = G[2], g3 = G[3];
  float g4 = G[4], g5 = G[5], g6 = G[6], g7 = G[7];
  const int pv = __ffs(Ml) - 1;
  const int lm = (1 << pv) - 1;
  float rar[8], rai[8], rbr[8], rbi[8];
  int via[8], vib[8];
#pragma unroll
  for (int it = 0; it < 8; it++) {
    int p = threadIdx.x + it * NT;
    int i0 = ((p >> pv) << (pv + 1)) | (p & lm);
    int i1 = i0 ^ Ml;
    int s = __popc(imap(i0) & selmask) & 1;
    int ia = s ? i1 : i0;   // selector-0 element
    int ib = s ? i0 : i1;   // selector-1 element
    via[it] = ia; vib[it] = ib;
    float ar = sre[ia], ai = sim[ia];
    float br = sre[ib], bi = sim[ib];
    rar[it] = g0 * ar - g1 * ai + g2 * br - g3 * bi;
    rai[it] = g0 * ai + g1 * ar + g2 * bi + g3 * br;
    rbr[it] = g4 * ar - g5 * ai + g6 * br - g7 * bi;
    rbi[it] = g4 * ai + g5 * ar + g6 * bi + g7 * br;
  }
  __syncthreads();
#pragma unroll
  for (int it = 0; it < 8; it++) {
    sre[via[it]] = rar[it]; sim[via[it]] = rai[it];
    sre[vib[it]] = rbr[it]; sim[vib[it]] = rbi[it];
  }
  __syncthreads();
}

// ---- Pass 1: layer-0 gates on bits 0..12 (qubits 15..3) ----
__global__ void __launch_bounds__(NT) pass1_k(const float* __restrict__ gbuf,
                                              const float* __restrict__ xre,
                                              const float* __restrict__ xim,
                                              float2* __restrict__ ws) {
  __shared__ float sre[NLOC], sim[NLOC];
  int blk = blockIdx.x;
  int batch = blk >> 3, hi3 = blk & 7;
  int base = batch * 65536 + (hi3 << 13);
  for (int l = threadIdx.x; l < NLOC; l += NT) {
    sre[l] = xre[base + l];
    sim[l] = xim[base + l];
  }
  __syncthreads();
  Map1 im{hi3 << 13};
#pragma unroll
  for (int b = 0; b < 13; b++)
    apply_gate(sre, sim, gbuf + (15 - b) * 8, 1 << b, 1 << b, im);  // layer0, qubit 15-b
  for (int l = threadIdx.x; l < NLOC; l += NT)
    ws[base + l] = make_float2(sre[l], sim[l]);
}

// ---- Pass 2: layer-0 on bits 13..15; layer-1 conjugated on b in {0,1..9,14,15} ----
__global__ void __launch_bounds__(NT) pass2_k(const float* __restrict__ gbuf,
                                              float2* __restrict__ ws) {
  __shared__ float sre[NLOC], sim[NLOC];
  int blk = blockIdx.x;
  int batch = blk >> 3, mid3 = blk & 7;
  int bbase = batch * 65536;
  Map2 im{mid3 << 10};
  for (int l = threadIdx.x; l < NLOC; l += NT) {
    float2 v = ws[bbase + im(l)];
    sre[l] = v.x; sim[l] = v.y;
  }
  __syncthreads();
  // layer-0 on bits 13,14,15 = qubits 2,1,0 (local l-bits 10,11,12)
  apply_gate(sre, sim, gbuf + 2 * 8, 1 << 10, 1 << 13, im);
  apply_gate(sre, sim, gbuf + 1 * 8, 1 << 11, 1 << 14, im);
  apply_gate(sre, sim, gbuf + 0 * 8, 1 << 12, 1 << 15, im);
  // layer-1 conjugated by P (these all commute - distinct post-perm qubits):
  // b=15 (qubit 0): mask f(e15)={14,15} -> l{11,12}; sel = 0x7FFF
  apply_gate(sre, sim, gbuf + (16 + 0) * 8, 3 << 11, 0x7FFF, im);
  // b=14 (qubit 1): mask {13,14} -> l{10,11}; sel = 0xC000
  apply_gate(sre, sim, gbuf + (16 + 1) * 8, 3 << 10, 0xC000, im);
  // b=0  (qubit 15): mask f(e0)={0,14,15} -> l{0,11,12}; sel = 0xFFFF
  apply_gate(sre, sim, gbuf + (16 + 15) * 8, 0x1801, 0xFFFF, im);
  // b=1..9 (qubits 14..6): mask {b-1,b}; sel = 0xFFFF<<b
#pragma unroll
  for (int b = 1; b <= 9; b++)
    apply_gate(sre, sim, gbuf + (16 + 15 - b) * 8, 3 << (b - 1), (0xFFFF << b) & 0xFFFF, im);
  for (int l = threadIdx.x; l < NLOC; l += NT)
    ws[bbase + im(l)] = make_float2(sre[l], sim[l]);
}

// ---- Pass 3: gather C[j]=B[f(j)]; layer-1 standard on bits 10..13; out[f^{-1}(j)]=|amp|^2 ----
__global__ void __launch_bounds__(NT) pass3_k(const float* __restrict__ gbuf,
                                              const float2* __restrict__ ws,
                                              float* __restrict__ out) {
  __shared__ float sre[NLOC], sim[NLOC];
  int blk = blockIdx.x;
  int batch = blk >> 3, g3 = blk & 7;
  int bbase = batch * 65536;
  Map3 im{((g3 & 1) << 9) | ((g3 >> 1) << 14)};  // j9 from g3.0, j14..15 from g3.1-2
  for (int l = threadIdx.x; l < NLOC; l += NT) {
    int j = im(l);
    float2 v = ws[bbase + fperm(j)];
    sre[l] = v.x; sim[l] = v.y;
  }
  __syncthreads();
  // layer-1 on j-bits 10..13 = qubits 5..2 (l-bits 9..12)
  apply_gate(sre, sim, gbuf + (16 + 5) * 8, 1 << 9,  1 << 10, im);
  apply_gate(sre, sim, gbuf + (16 + 4) * 8, 1 << 10, 1 << 11, im);
  apply_gate(sre, sim, gbuf + (16 + 3) * 8, 1 << 11, 1 << 12, im);
  apply_gate(sre, sim, gbuf + (16 + 2) * 8, 1 << 12, 1 << 13, im);
  for (int l = threadIdx.x; l < NLOC; l += NT) {
    int j = im(l);
    float pr = sre[l] * sre[l] + sim[l] * sim[l];
    out[bbase + finv16(j)] = pr;
  }
}

extern "C" void kernel_launch(void* const* d_in, const int* in_sizes, int n_in,
                              void* d_out, int out_size, void* d_ws, size_t ws_size,
                              hipStream_t stream) {
  const float* th  = (const float*)d_in[0];   // (2,3,16)
  const float* xre = (const float*)d_in[1];   // (32,65536)
  const float* xim = (const float*)d_in[2];   // (32,65536)
  float* out = (float*)d_out;                 // (32,65536) fp32 probs

  // ws layout: [0..255] floats = gate table (32 gates x 8), then 2M float2 amplitudes (16 MB)
  float* gbuf = (float*)d_ws;
  float2* amp = (float2*)((float*)d_ws + 256);

  gates_k<<<1, 64, 0, stream>>>(th, gbuf);
  pass1_k<<<256, NT, 0, stream>>>(gbuf, xre, xim, amp);
  pass2_k<<<256, NT, 0, stream>>>(gbuf, amp);
  pass3_k<<<256, NT, 0, stream>>>(gbuf, amp, out);
}

// Round 2
// 108.786 us; speedup vs baseline: 1.2228x; 1.2228x over previous
//
#include <hip/hip_runtime.h>

// 16-qubit, 2-layer circuit, batch 32.  Circuit = P*R1*P*R0 (P = CNOT-ring permutation).
// f(i) = i ^ (i>>1) ^ (bit0(i)?0xC000:0);  f^{-1} = suffix-xor cascade.
// Register-tiled version: each thread holds 16 amps (4 bits) in VGPRs; gates on in-tile
// bits are register-only.  LDS only re-tiles between rounds (3 barriers/pass, pass3 LDS-free).
// Gate/selector assignment identical to the verified R1 kernel.

#define NT 512

__device__ __forceinline__ int fperm(int x) {
  int y = x ^ (x >> 1);
  y ^= (x & 1) ? 0xC000 : 0;
  return y & 0xFFFF;
}

__device__ __forceinline__ int finv16(int x) {
  int s = x;
  s ^= s >> 1; s ^= s >> 2; s ^= s >> 4; s ^= s >> 8;
  int b15 = ((s ^ (s >> 15)) & 1) << 15;
  return (s & 0x7FFF) | b15;
}

__device__ __forceinline__ int swz(int l) { return l ^ ((l >> 4) & 31); }

// ---- gate table: U^{(l)}_q = RZ*RY*RX, 32 gates x 8 floats ----
__global__ void gates_k(const float* __restrict__ th, float* __restrict__ gbuf) {
  int tid = threadIdx.x;
  if (tid < 32) {
    int l = tid >> 4, q = tid & 15;
    float tx = th[l * 48 + q], ty = th[l * 48 + 16 + q], tz = th[l * 48 + 32 + q];
    float cx, sx, cy, sy, cz, sz;
    sincosf(0.5f * tx, &sx, &cx);
    sincosf(0.5f * ty, &sy, &cy);
    sincosf(0.5f * tz, &sz, &cz);
    float m00r = cy * cx, m00i =  sy * sx;
    float m01r = -sy * cx, m01i = -cy * sx;
    float m10r =  sy * cx, m10i = -cy * sx;
    float m11r =  cy * cx, m11i = -sy * sx;
    float* G = gbuf + tid * 8;
    G[0] = cz * m00r + sz * m00i;  G[1] = cz * m00i - sz * m00r;
    G[2] = cz * m01r + sz * m01i;  G[3] = cz * m01i - sz * m01r;
    G[4] = cz * m10r - sz * m10i;  G[5] = cz * m10i + sz * m10r;
    G[6] = cz * m11r - sz * m11i;  G[7] = cz * m11i + sz * m11r;
  }
}

// Register gate on a 16-amp tile. MK = pair mask (k-space), SK = selector mask in-tile
// (k-space); c = parity of (selmask & out-of-tile index bits).  popc(MK&SK) odd for all
// gates used, so each pair has one role-0 / one role-1 element.  c swaps to XGX coeffs.
template <int MK, int SK>
__device__ __forceinline__ void greg(float (&ar)[16], float (&ai)[16],
                                     const float* __restrict__ G, int c) {
  const float4* G4 = (const float4*)G;
  float4 r0 = G4[0], r1 = G4[1];
  bool sw = (c != 0);
  float h00r = sw ? r1.z : r0.x, h00i = sw ? r1.w : r0.y;
  float h01r = sw ? r1.x : r0.z, h01i = sw ? r1.y : r0.w;
  float h10r = sw ? r0.z : r1.x, h10i = sw ? r0.w : r1.y;
  float h11r = sw ? r0.x : r1.z, h11i = sw ? r0.y : r1.w;
  constexpr int PV = MK & (-MK);
#pragma unroll
  for (int k = 0; k < 16; k++) {
    if (k & PV) continue;
    const int k2 = k ^ MK;
    const int p0 = __builtin_popcount(k & SK) & 1;
    const int ka = p0 ? k2 : k;   // role-0 when c==0
    const int kb = p0 ? k : k2;
    float xr = ar[ka], xi = ai[ka], yr = ar[kb], yi = ai[kb];
    ar[ka] = h00r * xr - h00i * xi + h01r * yr - h01i * yi;
    ai[ka] = h00r * xi + h00i * xr + h01r * yi + h01i * yr;
    ar[kb] = h10r * xr - h10i * xi + h11r * yr - h11i * yi;
    ai[kb] = h10r * xi + h10i * xr + h11r * yi + h11i * yr;
  }
}

// ---- Pass 1: layer-0 gates on bits 0..12; rounds {0-3},{4-7},{8-11},{0-2,12} ----
__global__ void __launch_bounds__(NT) pass1_k(const float* __restrict__ gbuf,
                                              const float* __restrict__ xre,
                                              const float* __restrict__ xim,
                                              float2* __restrict__ ws) {
  __shared__ float sre[8192], sim[8192];
  int t = threadIdx.x;
  int blk = blockIdx.x, batch = blk >> 3, hi3 = blk & 7;
  int base = batch * 65536 + (hi3 << 13);
  float ar[16], ai[16];

  // Round A: tile bits 0-3, l = (t<<4)|k, contiguous from global
  {
    const float4* xr4 = (const float4*)(xre + base + (t << 4));
    const float4* xi4 = (const float4*)(xim + base + (t << 4));
#pragma unroll
    for (int q = 0; q < 4; q++) {
      float4 v = xr4[q]; ar[4*q] = v.x; ar[4*q+1] = v.y; ar[4*q+2] = v.z; ar[4*q+3] = v.w;
      float4 w = xi4[q]; ai[4*q] = w.x; ai[4*q+1] = w.y; ai[4*q+2] = w.z; ai[4*q+3] = w.w;
    }
    greg<1, 1>(ar, ai, gbuf + 15 * 8, 0);
    greg<2, 2>(ar, ai, gbuf + 14 * 8, 0);
    greg<4, 4>(ar, ai, gbuf + 13 * 8, 0);
    greg<8, 8>(ar, ai, gbuf + 12 * 8, 0);
#pragma unroll
    for (int k = 0; k < 16; k++) { int s = swz((t << 4) | k); sre[s] = ar[k]; sim[s] = ai[k]; }
  }
  __syncthreads();
  // Round B: tile bits 4-7, l = (t&15) | (k<<4) | ((t>>4)<<8)
  {
#pragma unroll
    for (int k = 0; k < 16; k++) {
      int s = swz((t & 15) | (k << 4) | ((t >> 4) << 8));
      ar[k] = sre[s]; ai[k] = sim[s];
    }
    greg<1, 1>(ar, ai, gbuf + 11 * 8, 0);
    greg<2, 2>(ar, ai, gbuf + 10 * 8, 0);
    greg<4, 4>(ar, ai, gbuf + 9 * 8, 0);
    greg<8, 8>(ar, ai, gbuf + 8 * 8, 0);
#pragma unroll
    for (int k = 0; k < 16; k++) {
      int s = swz((t & 15) | (k << 4) | ((t >> 4) << 8));
      sre[s] = ar[k]; sim[s] = ai[k];
    }
  }
  __syncthreads();
  // Round C: tile bits 8-11, l = (t&255) | (k<<8) | ((t>>8)<<12)
  {
#pragma unroll
    for (int k = 0; k < 16; k++) {
      int s = swz((t & 255) | (k << 8) | ((t >> 8) << 12));
      ar[k] = sre[s]; ai[k] = sim[s];
    }
    greg<1, 1>(ar, ai, gbuf + 7 * 8, 0);
    greg<2, 2>(ar, ai, gbuf + 6 * 8, 0);
    greg<4, 4>(ar, ai, gbuf + 5 * 8, 0);
    greg<8, 8>(ar, ai, gbuf + 4 * 8, 0);
#pragma unroll
    for (int k = 0; k < 16; k++) {
      int s = swz((t & 255) | (k << 8) | ((t >> 8) << 12));
      sre[s] = ar[k]; sim[s] = ai[k];
    }
  }
  __syncthreads();
  // Round D: tile bits {0,1,2,12}, l = (k&7) | (t<<3) | ((k>>3)<<12); gate bit12 = k-bit3
  {
#pragma unroll
    for (int k = 0; k < 16; k++) {
      int s = swz((k & 7) | (t << 3) | ((k >> 3) << 12));
      ar[k] = sre[s]; ai[k] = sim[s];
    }
    greg<8, 8>(ar, ai, gbuf + 3 * 8, 0);
#pragma unroll
    for (int k = 0; k < 16; k += 2) {
      float4* p = (float4*)(ws + base + (k & 7) + (t << 3) + ((k >> 3) << 12));
      *p = make_float4(ar[k], ai[k], ar[k + 1], ai[k + 1]);
    }
  }
}

// ---- Pass 2: layer-0 on bits 13-15, conjugated layer-1 on b in {0,1..9,14,15} ----
__global__ void __launch_bounds__(NT) pass2_k(const float* __restrict__ gbuf,
                                              float2* __restrict__ ws) {
  __shared__ float sre[8192], sim[8192];
  int t = threadIdx.x;
  int blk = blockIdx.x, batch = blk >> 3, mid3 = blk & 7;
  int bbase = batch * 65536, mb = mid3 << 10;
  float ar[16], ai[16];

  // Round A': tile {l0,l10,l11,l12}: l = (k&1) | (t<<1) | ((k>>1)<<10)
  // full idx: bit0=k0, bits1-9=t, bits10-12=mb, bit13=k1, bit14=k2, bit15=k3
  {
#pragma unroll
    for (int k = 0; k < 16; k += 2) {
      int f2 = (k & 1) | (t << 1) | mb | ((k >> 1) << 13);
      float4 v = *(const float4*)(ws + bbase + f2);
      ar[k] = v.x; ai[k] = v.y; ar[k + 1] = v.z; ai[k + 1] = v.w;
    }
    int fbase = (t << 1) | mb;                  // bits <=12 only
    int codd = __popc(fbase) & 1;               // parity over 0x7FFF == 0xFFFF here
    greg<2, 2>(ar, ai, gbuf + 2 * 8, 0);        // layer0 bit13
    greg<4, 4>(ar, ai, gbuf + 1 * 8, 0);        // layer0 bit14
    greg<8, 8>(ar, ai, gbuf + 0 * 8, 0);        // layer0 bit15
    greg<12, 7>(ar, ai, gbuf + (16 + 0) * 8, codd);   // conj b=15, sel 0x7FFF
    greg<6, 12>(ar, ai, gbuf + (16 + 1) * 8, 0);      // conj b=14, sel 0xC000 (fbase part = 0)
    greg<13, 15>(ar, ai, gbuf + (16 + 15) * 8, codd); // conj b=0,  sel 0xFFFF
#pragma unroll
    for (int k = 0; k < 16; k++) {
      int s = swz((k & 1) | (t << 1) | ((k >> 1) << 10));
      sre[s] = ar[k]; sim[s] = ai[k];
    }
  }
  __syncthreads();
  // Round B': tile {l0..l3}: l = k | (t<<4); conj b=1,2,3
  {
#pragma unroll
    for (int k = 0; k < 16; k++) {
      int s = swz(k | (t << 4)); ar[k] = sre[s]; ai[k] = sim[s];
    }
    int lA = t << 4;
    int fbase = (lA & 1023) | mb | ((lA >> 10) << 13);
    int c = __popc(fbase) & 1;                  // equal for sel 0xFFFE/0xFFFC/0xFFF8
    greg<3, 14>(ar, ai, gbuf + (16 + 14) * 8, c);
    greg<6, 12>(ar, ai, gbuf + (16 + 13) * 8, c);
    greg<12, 8>(ar, ai, gbuf + (16 + 12) * 8, c);
#pragma unroll
    for (int k = 0; k < 16; k++) {
      int s = swz(k | (t << 4)); sre[s] = ar[k]; sim[s] = ai[k];
    }
  }
  __syncthreads();
  // Round C': tile {l3..l6}: l = (t&7) | (k<<3) | ((t>>3)<<7); conj b=4,5,6
  {
#pragma unroll
    for (int k = 0; k < 16; k++) {
      int s = swz((t & 7) | (k << 3) | ((t >> 3) << 7));
      ar[k] = sre[s]; ai[k] = sim[s];
    }
    int lA = (t & 7) | ((t >> 3) << 7);
    int fbase = (lA & 1023) | mb | ((lA >> 10) << 13);
    int c = __popc(fbase & 0xFFF0) & 1;         // equal for sel 0xFFF0/0xFFE0/0xFFC0
    greg<3, 14>(ar, ai, gbuf + (16 + 11) * 8, c);
    greg<6, 12>(ar, ai, gbuf + (16 + 10) * 8, c);
    greg<12, 8>(ar, ai, gbuf + (16 + 9) * 8, c);
#pragma unroll
    for (int k = 0; k < 16; k++) {
      int s = swz((t & 7) | (k << 3) | ((t >> 3) << 7));
      sre[s] = ar[k]; sim[s] = ai[k];
    }
  }
  __syncthreads();
  // Round D': tile {l6..l9}: l = (t&63) | (k<<6) | ((t>>6)<<10); conj b=7,8,9; store out
  {
#pragma unroll
    for (int k = 0; k < 16; k++) {
      int s = swz((t & 63) | (k << 6) | ((t >> 6) << 10));
      ar[k] = sre[s]; ai[k] = sim[s];
    }
    int lA = (t & 63) | ((t >> 6) << 10);
    int fbase = (lA & 1023) | mb | ((lA >> 10) << 13);
    int c = __popc(fbase & 0xFF80) & 1;         // equal for sel 0xFF80/0xFF00/0xFE00
    greg<3, 14>(ar, ai, gbuf + (16 + 8) * 8, c);
    greg<6, 12>(ar, ai, gbuf + (16 + 7) * 8, c);
    greg<12, 8>(ar, ai, gbuf + (16 + 6) * 8, c);
#pragma unroll
    for (int k = 0; k < 16; k++) {
      int f2 = (t & 63) | (k << 6) | mb | ((t >> 6) << 13);
      ws[bbase + f2] = make_float2(ar[k], ai[k]);
    }
  }
}

// ---- Pass 3: LDS-free. Gather B[f(j)] into registers, layer-1 on j-bits 10..13,
//      out[f^{-1}(j)] = |amp|^2 ----
__global__ void __launch_bounds__(NT) pass3_k(const float* __restrict__ gbuf,
                                              const float2* __restrict__ ws,
                                              float* __restrict__ out) {
  int t = threadIdx.x;
  int blk = blockIdx.x, batch = blk >> 3, g3 = blk & 7;
  int bbase = batch * 65536;
  int gb = ((g3 & 1) << 9) | ((g3 >> 1) << 14);
  int jt = (t & 0x1FF) | gb;
  float ar[16], ai[16];
#pragma unroll
  for (int k = 0; k < 16; k++) {
    int j = jt | (k << 10);
    float2 v = ws[bbase + fperm(j)];
    ar[k] = v.x; ai[k] = v.y;
  }
  greg<1, 1>(ar, ai, gbuf + (16 + 5) * 8, 0);   // bit10
  greg<2, 2>(ar, ai, gbuf + (16 + 4) * 8, 0);   // bit11
  greg<4, 4>(ar, ai, gbuf + (16 + 3) * 8, 0);   // bit12
  greg<8, 8>(ar, ai, gbuf + (16 + 2) * 8, 0);   // bit13
#pragma unroll
  for (int k = 0; k < 16; k++) {
    int j = jt | (k << 10);
    out[bbase + finv16(j)] = ar[k] * ar[k] + ai[k] * ai[k];
  }
}

extern "C" void kernel_launch(void* const* d_in, const int* in_sizes, int n_in,
                              void* d_out, int out_size, void* d_ws, size_t ws_size,
                              hipStream_t stream) {
  const float* th  = (const float*)d_in[0];   // (2,3,16)
  const float* xre = (const float*)d_in[1];   // (32,65536)
  const float* xim = (const float*)d_in[2];   // (32,65536)
  float* out = (float*)d_out;                 // (32,65536) fp32

  float* gbuf = (float*)d_ws;                 // 32 gates x 8 floats
  float2* amp = (float2*)((float*)d_ws + 256);

  gates_k<<<1, 64, 0, stream>>>(th, gbuf);
  pass1_k<<<256, NT, 0, stream>>>(gbuf, xre, xim, amp);
  pass2_k<<<256, NT, 0, stream>>>(gbuf, amp);
  pass3_k<<<256, NT, 0, stream>>>(gbuf, amp, out);
}

// Round 3
// 104.166 us; speedup vs baseline: 1.2770x; 1.0444x over previous
//
#include <hip/hip_runtime.h>

// 16-qubit, 2-layer circuit, batch 32.  Circuit = P*R1*P*R0 (P = CNOT-ring permutation).
// f(i) = i ^ (i>>1) ^ (bit0(i)?0xC000:0);  f^{-1} = suffix-xor cascade.
// 12-bit windows (4K amps, 32KB LDS, 256 thr x 16 amps) for 2 blocks/CU co-residency.
// Pass1: R0 on bits 0-11 (3 rounds). Pass2: R0 12-15 + conj b in {0..7,13,14,15} (4 rounds).
// Pass3: gather B[f(j)], standard gates on j-bits 8-12 (32-amp register tile), out=|.|^2.
// Gate table computed per-block into LDS (no separate kernel).

#define NT 256

__device__ __forceinline__ int fperm(int x) {
  int y = x ^ (x >> 1);
  y ^= (x & 1) ? 0xC000 : 0;
  return y & 0xFFFF;
}

__device__ __forceinline__ int finv16(int x) {
  int s = x;
  s ^= s >> 1; s ^= s >> 2; s ^= s >> 4; s ^= s >> 8;
  int b15 = ((s ^ (s >> 15)) & 1) << 15;
  return (s & 0x7FFF) | b15;
}

__device__ __forceinline__ int swz1(int l) { return l ^ ((l >> 4) & 31); }
__device__ __forceinline__ int swz2(int l) { return l ^ ((l >> 5) & 31); }

// Compute all 32 fused gates U^{(l)}_q = RZ*RY*RX into gsh (32 x 8 floats). Lanes 0-31.
__device__ __forceinline__ void compute_gates(const float* __restrict__ th, float* gsh) {
  int tid = threadIdx.x;
  if (tid < 32) {
    int l = tid >> 4, q = tid & 15;
    float tx = th[l * 48 + q], ty = th[l * 48 + 16 + q], tz = th[l * 48 + 32 + q];
    float cx, sx, cy, sy, cz, sz;
    sincosf(0.5f * tx, &sx, &cx);
    sincosf(0.5f * ty, &sy, &cy);
    sincosf(0.5f * tz, &sz, &cz);
    float m00r = cy * cx, m00i =  sy * sx;
    float m01r = -sy * cx, m01i = -cy * sx;
    float m10r =  sy * cx, m10i = -cy * sx;
    float m11r =  cy * cx, m11i = -sy * sx;
    float* G = gsh + tid * 8;
    G[0] = cz * m00r + sz * m00i;  G[1] = cz * m00i - sz * m00r;
    G[2] = cz * m01r + sz * m01i;  G[3] = cz * m01i - sz * m01r;
    G[4] = cz * m10r - sz * m10i;  G[5] = cz * m10i + sz * m10r;
    G[6] = cz * m11r - sz * m11i;  G[7] = cz * m11i + sz * m11r;
  }
}

// Register gate on an N-amp tile. MK = pair mask (k-space), SK = in-tile selector mask;
// c = parity of (selector & out-of-tile index bits). popc(MK&SK) odd for all uses.
template <int MK, int SK, int N>
__device__ __forceinline__ void greg(float (&ar)[N], float (&ai)[N],
                                     const float* G, int c) {
  const float4* G4 = (const float4*)G;
  float4 r0 = G4[0], r1 = G4[1];
  bool sw = (c != 0);
  float h00r = sw ? r1.z : r0.x, h00i = sw ? r1.w : r0.y;
  float h01r = sw ? r1.x : r0.z, h01i = sw ? r1.y : r0.w;
  float h10r = sw ? r0.z : r1.x, h10i = sw ? r0.w : r1.y;
  float h11r = sw ? r0.x : r1.z, h11i = sw ? r0.y : r1.w;
  constexpr int PV = MK & (-MK);
#pragma unroll
  for (int k = 0; k < N; k++) {
    if (k & PV) continue;
    const int k2 = k ^ MK;
    const int p0 = __builtin_popcount(k & SK) & 1;
    const int ka = p0 ? k2 : k;
    const int kb = p0 ? k : k2;
    float xr = ar[ka], xi = ai[ka], yr = ar[kb], yi = ai[kb];
    ar[ka] = h00r * xr - h00i * xi + h01r * yr - h01i * yi;
    ai[ka] = h00r * xi + h00i * xr + h01r * yi + h01i * yr;
    ar[kb] = h10r * xr - h10i * xi + h11r * yr - h11i * yi;
    ai[kb] = h10r * xi + h10i * xr + h11r * yi + h11i * yr;
  }
}

// ---- Pass 1: R0 on bits 0..11.  Window = batch x bits 12-15.  512 blocks. ----
__global__ void __launch_bounds__(NT) pass1_k(const float* __restrict__ th,
                                              const float* __restrict__ xre,
                                              const float* __restrict__ xim,
                                              float2* __restrict__ ws) {
  __shared__ float gsh[256];
  __shared__ float sre[4096], sim[4096];
  int t = threadIdx.x;
  int blk = blockIdx.x, batch = blk >> 4, wb = blk & 15;
  int base = batch * 65536 + (wb << 12);
  float ar[16], ai[16];

  compute_gates(th, gsh);
  // Round A: tile bits 0-3, l = (t<<4)|k, contiguous from global
  {
    const float4* xr4 = (const float4*)(xre + base + (t << 4));
    const float4* xi4 = (const float4*)(xim + base + (t << 4));
#pragma unroll
    for (int q = 0; q < 4; q++) {
      float4 v = xr4[q]; ar[4*q] = v.x; ar[4*q+1] = v.y; ar[4*q+2] = v.z; ar[4*q+3] = v.w;
      float4 w = xi4[q]; ai[4*q] = w.x; ai[4*q+1] = w.y; ai[4*q+2] = w.z; ai[4*q+3] = w.w;
    }
  }
  __syncthreads();   // gsh ready
  greg<1, 1>(ar, ai, gsh + 15 * 8, 0);
  greg<2, 2>(ar, ai, gsh + 14 * 8, 0);
  greg<4, 4>(ar, ai, gsh + 13 * 8, 0);
  greg<8, 8>(ar, ai, gsh + 12 * 8, 0);
#pragma unroll
  for (int k = 0; k < 16; k++) { int s = swz1((t << 4) | k); sre[s] = ar[k]; sim[s] = ai[k]; }
  __syncthreads();
  // Round B: tile bits 4-7, l = (t&15) | (k<<4) | ((t>>4)<<8)
#pragma unroll
  for (int k = 0; k < 16; k++) {
    int s = swz1((t & 15) | (k << 4) | ((t >> 4) << 8));
    ar[k] = sre[s]; ai[k] = sim[s];
  }
  greg<1, 1>(ar, ai, gsh + 11 * 8, 0);
  greg<2, 2>(ar, ai, gsh + 10 * 8, 0);
  greg<4, 4>(ar, ai, gsh + 9 * 8, 0);
  greg<8, 8>(ar, ai, gsh + 8 * 8, 0);
#pragma unroll
  for (int k = 0; k < 16; k++) {
    int s = swz1((t & 15) | (k << 4) | ((t >> 4) << 8));
    sre[s] = ar[k]; sim[s] = ai[k];
  }
  __syncthreads();
  // Round C: tile bits 8-11, l = t | (k<<8)
#pragma unroll
  for (int k = 0; k < 16; k++) {
    int s = swz1(t | (k << 8)); ar[k] = sre[s]; ai[k] = sim[s];
  }
  greg<1, 1>(ar, ai, gsh + 7 * 8, 0);
  greg<2, 2>(ar, ai, gsh + 6 * 8, 0);
  greg<4, 4>(ar, ai, gsh + 5 * 8, 0);
  greg<8, 8>(ar, ai, gsh + 4 * 8, 0);
#pragma unroll
  for (int k = 0; k < 16; k++)
    ws[base + t + (k << 8)] = make_float2(ar[k], ai[k]);
}

// ---- Pass 2: R0 on bits 12-15; conj-R1 b in {0..7,13,14,15}.  Window = batch x bits 8-11. ----
__global__ void __launch_bounds__(NT) pass2_k(const float* __restrict__ th,
                                              float2* __restrict__ ws) {
  __shared__ float gsh[256];
  __shared__ float sre[4096], sim[4096];
  int t = threadIdx.x;
  int blk = blockIdx.x, batch = blk >> 4, wb = blk & 15;
  int bbase = batch * 65536;
  float ar[16], ai[16];

  compute_gates(th, gsh);
  // Round A: tile full {12,13,14,15}, l = t | (k<<8)
#pragma unroll
  for (int k = 0; k < 16; k++) {
    float2 v = ws[bbase + t + (wb << 8) + (k << 12)];
    ar[k] = v.x; ai[k] = v.y;
  }
  __syncthreads();   // gsh ready
  int cA = (__popc(t) + __popc(wb)) & 1;   // parity of full bits 0..11
  greg<1, 1>(ar, ai, gsh + 3 * 8, 0);      // R0 bit12 (qubit 3)
  greg<2, 2>(ar, ai, gsh + 2 * 8, 0);      // R0 bit13
  greg<4, 4>(ar, ai, gsh + 1 * 8, 0);      // R0 bit14
  greg<8, 8>(ar, ai, gsh + 0 * 8, 0);      // R0 bit15
  greg<12, 7>(ar, ai, gsh + (16 + 0) * 8, cA);  // conj b=15: pair {14,15}, sel 0x7FFF
  greg<6, 12>(ar, ai, gsh + (16 + 1) * 8, 0);   // conj b=14: pair {13,14}, sel 0xC000
  greg<3, 14>(ar, ai, gsh + (16 + 2) * 8, 0);   // conj b=13: pair {12,13}, sel 0xE000
#pragma unroll
  for (int k = 0; k < 16; k++) {
    int s = swz2(t | (k << 8)); sre[s] = ar[k]; sim[s] = ai[k];
  }
  __syncthreads();
  // Round B: tile full {0,1,14,15}: l = (k&3) | (t<<2) | ((k>>2)<<10)
#pragma unroll
  for (int k = 0; k < 16; k++) {
    int s = swz2((k & 3) | (t << 2) | ((k >> 2) << 10));
    ar[k] = sre[s]; ai[k] = sim[s];
  }
  greg<13, 15>(ar, ai, gsh + (16 + 15) * 8, cA); // conj b=0: pair {0,14,15}, sel 0xFFFF
  greg<3, 14>(ar, ai, gsh + (16 + 14) * 8, cA);  // conj b=1: pair {0,1}, sel 0xFFFE
#pragma unroll
  for (int k = 0; k < 16; k++) {
    int s = swz2((k & 3) | (t << 2) | ((k >> 2) << 10));
    sre[s] = ar[k]; sim[s] = ai[k];
  }
  __syncthreads();
  // Round C: tile full {1,2,3,4}: l = (t&1) | (k<<1) | ((t>>1)<<5)
#pragma unroll
  for (int k = 0; k < 16; k++) {
    int s = swz2((t & 1) | (k << 1) | ((t >> 1) << 5));
    ar[k] = sre[s]; ai[k] = sim[s];
  }
  {
    int cC = (__popc(t >> 1) + __popc(wb)) & 1;  // parity of full bits 5..15
    greg<3, 14>(ar, ai, gsh + (16 + 13) * 8, cC);  // conj b=2
    greg<6, 12>(ar, ai, gsh + (16 + 12) * 8, cC);  // conj b=3
    greg<12, 8>(ar, ai, gsh + (16 + 11) * 8, cC);  // conj b=4
  }
#pragma unroll
  for (int k = 0; k < 16; k++) {
    int s = swz2((t & 1) | (k << 1) | ((t >> 1) << 5));
    sre[s] = ar[k]; sim[s] = ai[k];
  }
  __syncthreads();
  // Round D: tile full {4,5,6,7}: l = (t&15) | (k<<4) | ((t>>4)<<8); store out
#pragma unroll
  for (int k = 0; k < 16; k++) {
    int s = swz2((t & 15) | (k << 4) | ((t >> 4) << 8));
    ar[k] = sre[s]; ai[k] = sim[s];
  }
  {
    int cD = (__popc(t >> 4) + __popc(wb)) & 1;  // parity of full bits 8..15
    greg<3, 14>(ar, ai, gsh + (16 + 10) * 8, cD);  // conj b=5
    greg<6, 12>(ar, ai, gsh + (16 + 9) * 8, cD);   // conj b=6
    greg<12, 8>(ar, ai, gsh + (16 + 8) * 8, cD);   // conj b=7
  }
#pragma unroll
  for (int k = 0; k < 16; k++) {
    int full = (t & 15) | (k << 4) | (wb << 8) | ((t >> 4) << 12);
    ws[bbase + full] = make_float2(ar[k], ai[k]);
  }
}

// ---- Pass 3: gather C[j]=B[f(j)]; standard gates on j-bits 8-12 (32-amp reg tile);
//      out[f^{-1}(j)] = |amp|^2.  256 blocks x 256 threads. ----
__global__ void __launch_bounds__(NT) pass3_k(const float* __restrict__ th,
                                              const float2* __restrict__ ws,
                                              float* __restrict__ out) {
  __shared__ float gsh[256];
  int t = threadIdx.x;
  int blk = blockIdx.x, batch = blk >> 3, g3 = blk & 7;
  int bbase = batch * 65536;
  int jt = t | (g3 << 13);
  float ar[32], ai[32];
  compute_gates(th, gsh);
#pragma unroll
  for (int k = 0; k < 32; k++) {
    int j = jt | (k << 8);
    float2 v = ws[bbase + fperm(j)];
    ar[k] = v.x; ai[k] = v.y;
  }
  __syncthreads();   // gsh ready
  greg<1, 1>(ar, ai, gsh + (16 + 7) * 8, 0);    // b=8  (qubit 7)
  greg<2, 2>(ar, ai, gsh + (16 + 6) * 8, 0);    // b=9
  greg<4, 4>(ar, ai, gsh + (16 + 5) * 8, 0);    // b=10
  greg<8, 8>(ar, ai, gsh + (16 + 4) * 8, 0);    // b=11
  greg<16, 16>(ar, ai, gsh + (16 + 3) * 8, 0);  // b=12
#pragma unroll
  for (int k = 0; k < 32; k++) {
    int j = jt | (k << 8);
    out[bbase + finv16(j)] = ar[k] * ar[k] + ai[k] * ai[k];
  }
}

extern "C" void kernel_launch(void* const* d_in, const int* in_sizes, int n_in,
                              void* d_out, int out_size, void* d_ws, size_t ws_size,
                              hipStream_t stream) {
  const float* th  = (const float*)d_in[0];   // (2,3,16)
  const float* xre = (const float*)d_in[1];   // (32,65536)
  const float* xim = (const float*)d_in[2];   // (32,65536)
  float* out = (float*)d_out;                 // (32,65536) fp32

  float2* amp = (float2*)d_ws;                // 2M float2 = 16 MB

  pass1_k<<<512, NT, 0, stream>>>(th, xre, xim, amp);
  pass2_k<<<512, NT, 0, stream>>>(th, amp);
  pass3_k<<<256, NT, 0, stream>>>(th, amp, out);
}

// Round 5
// 104.021 us; speedup vs baseline: 1.2788x; 1.0014x over previous
//
#include <hip/hip_runtime.h>

// 16-qubit, 2-layer circuit, batch 32.  Circuit = P*R1*P*R0 (P = CNOT-ring permutation).
// f(i) = i ^ (i>>1) ^ (bit0(i)?0xC000:0);  f^{-1} = suffix-xor cascade.
// Cooperative fused kernel (3 phases, per-batch atomic producer/consumer sync) with
// occupancy pre-check + return-code-checked fallback to the verified R3 3-kernel path.

#define NT 256

__device__ __forceinline__ int fperm(int x) {
  int y = x ^ (x >> 1);
  y ^= (x & 1) ? 0xC000 : 0;
  return y & 0xFFFF;
}

__device__ __forceinline__ int finv16(int x) {
  int s = x;
  s ^= s >> 1; s ^= s >> 2; s ^= s >> 4; s ^= s >> 8;
  int b15 = ((s ^ (s >> 15)) & 1) << 15;
  return (s & 0x7FFF) | b15;
}

__device__ __forceinline__ int swz1(int l) { return l ^ ((l >> 4) & 31); }
__device__ __forceinline__ int swz2(int l) { return l ^ ((l >> 5) & 31); }

__device__ __forceinline__ void compute_gates(const float* __restrict__ th, float* gsh) {
  int tid = threadIdx.x;
  if (tid < 32) {
    int l = tid >> 4, q = tid & 15;
    float tx = th[l * 48 + q], ty = th[l * 48 + 16 + q], tz = th[l * 48 + 32 + q];
    float cx, sx, cy, sy, cz, sz;
    sincosf(0.5f * tx, &sx, &cx);
    sincosf(0.5f * ty, &sy, &cy);
    sincosf(0.5f * tz, &sz, &cz);
    float m00r = cy * cx, m00i =  sy * sx;
    float m01r = -sy * cx, m01i = -cy * sx;
    float m10r =  sy * cx, m10i = -cy * sx;
    float m11r =  cy * cx, m11i = -sy * sx;
    float* G = gsh + tid * 8;
    G[0] = cz * m00r + sz * m00i;  G[1] = cz * m00i - sz * m00r;
    G[2] = cz * m01r + sz * m01i;  G[3] = cz * m01i - sz * m01r;
    G[4] = cz * m10r - sz * m10i;  G[5] = cz * m10i + sz * m10r;
    G[6] = cz * m11r - sz * m11i;  G[7] = cz * m11i + sz * m11r;
  }
}

template <int MK, int SK, int N>
__device__ __forceinline__ void greg(float (&ar)[N], float (&ai)[N],
                                     const float* G, int c) {
  const float4* G4 = (const float4*)G;
  float4 r0 = G4[0], r1 = G4[1];
  bool sw = (c != 0);
  float h00r = sw ? r1.z : r0.x, h00i = sw ? r1.w : r0.y;
  float h01r = sw ? r1.x : r0.z, h01i = sw ? r1.y : r0.w;
  float h10r = sw ? r0.z : r1.x, h10i = sw ? r0.w : r1.y;
  float h11r = sw ? r0.x : r1.z, h11i = sw ? r0.y : r1.w;
  constexpr int PV = MK & (-MK);
#pragma unroll
  for (int k = 0; k < N; k++) {
    if (k & PV) continue;
    const int k2 = k ^ MK;
    const int p0 = __builtin_popcount(k & SK) & 1;
    const int ka = p0 ? k2 : k;
    const int kb = p0 ? k : k2;
    float xr = ar[ka], xi = ai[ka], yr = ar[kb], yi = ai[kb];
    ar[ka] = h00r * xr - h00i * xi + h01r * yr - h01i * yi;
    ai[ka] = h00r * xi + h00i * xr + h01r * yi + h01i * yr;
    ar[kb] = h10r * xr - h10i * xi + h11r * yr - h11i * yi;
    ai[kb] = h10r * xi + h10i * xr + h11r * yi + h11i * yr;
  }
}

// ====================== Phase bodies as device functions ======================

__device__ __forceinline__ void phaseA_body(int t, int bbase, int wb,
                                            const float* gsh,
                                            float* sre, float* sim,
                                            const float* __restrict__ xre,
                                            const float* __restrict__ xim,
                                            float2* __restrict__ ws) {
  float ar[16], ai[16];
  int base = bbase + (wb << 12);
  const float4* xr4 = (const float4*)(xre + base + (t << 4));
  const float4* xi4 = (const float4*)(xim + base + (t << 4));
#pragma unroll
  for (int q = 0; q < 4; q++) {
    float4 v = xr4[q]; ar[4*q] = v.x; ar[4*q+1] = v.y; ar[4*q+2] = v.z; ar[4*q+3] = v.w;
    float4 w = xi4[q]; ai[4*q] = w.x; ai[4*q+1] = w.y; ai[4*q+2] = w.z; ai[4*q+3] = w.w;
  }
  __syncthreads();   // gsh ready (and sre/sim free)
  greg<1, 1>(ar, ai, gsh + 15 * 8, 0);
  greg<2, 2>(ar, ai, gsh + 14 * 8, 0);
  greg<4, 4>(ar, ai, gsh + 13 * 8, 0);
  greg<8, 8>(ar, ai, gsh + 12 * 8, 0);
#pragma unroll
  for (int k = 0; k < 16; k++) { int s = swz1((t << 4) | k); sre[s] = ar[k]; sim[s] = ai[k]; }
  __syncthreads();
#pragma unroll
  for (int k = 0; k < 16; k++) {
    int s = swz1((t & 15) | (k << 4) | ((t >> 4) << 8));
    ar[k] = sre[s]; ai[k] = sim[s];
  }
  greg<1, 1>(ar, ai, gsh + 11 * 8, 0);
  greg<2, 2>(ar, ai, gsh + 10 * 8, 0);
  greg<4, 4>(ar, ai, gsh + 9 * 8, 0);
  greg<8, 8>(ar, ai, gsh + 8 * 8, 0);
#pragma unroll
  for (int k = 0; k < 16; k++) {
    int s = swz1((t & 15) | (k << 4) | ((t >> 4) << 8));
    sre[s] = ar[k]; sim[s] = ai[k];
  }
  __syncthreads();
#pragma unroll
  for (int k = 0; k < 16; k++) {
    int s = swz1(t | (k << 8)); ar[k] = sre[s]; ai[k] = sim[s];
  }
  greg<1, 1>(ar, ai, gsh + 7 * 8, 0);
  greg<2, 2>(ar, ai, gsh + 6 * 8, 0);
  greg<4, 4>(ar, ai, gsh + 5 * 8, 0);
  greg<8, 8>(ar, ai, gsh + 4 * 8, 0);
#pragma unroll
  for (int k = 0; k < 16; k++)
    ws[base + t + (k << 8)] = make_float2(ar[k], ai[k]);
}

__device__ __forceinline__ void phaseB_body(int t, int bbase, int wb,
                                            const float* gsh,
                                            float* sre, float* sim,
                                            float2* __restrict__ ws) {
  float ar[16], ai[16];
#pragma unroll
  for (int k = 0; k < 16; k++) {
    float2 v = ws[bbase + t + (wb << 8) + (k << 12)];
    ar[k] = v.x; ai[k] = v.y;
  }
  int cA = (__popc(t) + __popc(wb)) & 1;   // parity of full bits 0..11
  greg<1, 1>(ar, ai, gsh + 3 * 8, 0);
  greg<2, 2>(ar, ai, gsh + 2 * 8, 0);
  greg<4, 4>(ar, ai, gsh + 1 * 8, 0);
  greg<8, 8>(ar, ai, gsh + 0 * 8, 0);
  greg<12, 7>(ar, ai, gsh + (16 + 0) * 8, cA);
  greg<6, 12>(ar, ai, gsh + (16 + 1) * 8, 0);
  greg<3, 14>(ar, ai, gsh + (16 + 2) * 8, 0);
  __syncthreads();   // sre/sim free
#pragma unroll
  for (int k = 0; k < 16; k++) {
    int s = swz2(t | (k << 8)); sre[s] = ar[k]; sim[s] = ai[k];
  }
  __syncthreads();
#pragma unroll
  for (int k = 0; k < 16; k++) {
    int s = swz2((k & 3) | (t << 2) | ((k >> 2) << 10));
    ar[k] = sre[s]; ai[k] = sim[s];
  }
  greg<13, 15>(ar, ai, gsh + (16 + 15) * 8, cA);
  greg<3, 14>(ar, ai, gsh + (16 + 14) * 8, cA);
#pragma unroll
  for (int k = 0; k < 16; k++) {
    int s = swz2((k & 3) | (t << 2) | ((k >> 2) << 10));
    sre[s] = ar[k]; sim[s] = ai[k];
  }
  __syncthreads();
#pragma unroll
  for (int k = 0; k < 16; k++) {
    int s = swz2((t & 1) | (k << 1) | ((t >> 1) << 5));
    ar[k] = sre[s]; ai[k] = sim[s];
  }
  {
    int cC = (__popc(t >> 1) + __popc(wb)) & 1;
    greg<3, 14>(ar, ai, gsh + (16 + 13) * 8, cC);
    greg<6, 12>(ar, ai, gsh + (16 + 12) * 8, cC);
    greg<12, 8>(ar, ai, gsh + (16 + 11) * 8, cC);
  }
#pragma unroll
  for (int k = 0; k < 16; k++) {
    int s = swz2((t & 1) | (k << 1) | ((t >> 1) << 5));
    sre[s] = ar[k]; sim[s] = ai[k];
  }
  __syncthreads();
#pragma unroll
  for (int k = 0; k < 16; k++) {
    int s = swz2((t & 15) | (k << 4) | ((t >> 4) << 8));
    ar[k] = sre[s]; ai[k] = sim[s];
  }
  {
    int cD = (__popc(t >> 4) + __popc(wb)) & 1;
    greg<3, 14>(ar, ai, gsh + (16 + 10) * 8, cD);
    greg<6, 12>(ar, ai, gsh + (16 + 9) * 8, cD);
    greg<12, 8>(ar, ai, gsh + (16 + 8) * 8, cD);
  }
#pragma unroll
  for (int k = 0; k < 16; k++) {
    int full = (t & 15) | (k << 4) | (wb << 8) | ((t >> 4) << 12);
    ws[bbase + full] = make_float2(ar[k], ai[k]);
  }
}

__device__ __forceinline__ void phaseC_body(int t, int bbase3, int g3,
                                            const float* gsh,
                                            const float2* __restrict__ ws,
                                            float* __restrict__ out) {
  int jt = t | (g3 << 13);
  float br[32], bi[32];
#pragma unroll
  for (int k = 0; k < 32; k++) {
    int j = jt | (k << 8);
    float2 v = ws[bbase3 + fperm(j)];
    br[k] = v.x; bi[k] = v.y;
  }
  greg<1, 1>(br, bi, gsh + (16 + 7) * 8, 0);
  greg<2, 2>(br, bi, gsh + (16 + 6) * 8, 0);
  greg<4, 4>(br, bi, gsh + (16 + 5) * 8, 0);
  greg<8, 8>(br, bi, gsh + (16 + 4) * 8, 0);
  greg<16, 16>(br, bi, gsh + (16 + 3) * 8, 0);
#pragma unroll
  for (int k = 0; k < 32; k++) {
    int j = jt | (k << 8);
    out[bbase3 + finv16(j)] = br[k] * br[k] + bi[k] * bi[k];
  }
}

// ====================== Fallback: verified R3 three-kernel path ======================

__global__ void __launch_bounds__(NT) pass1_k(const float* __restrict__ th,
                                              const float* __restrict__ xre,
                                              const float* __restrict__ xim,
                                              float2* __restrict__ ws) {
  __shared__ float gsh[256];
  __shared__ float sre[4096], sim[4096];
  int t = threadIdx.x;
  int blk = blockIdx.x, batch = blk >> 4, wb = blk & 15;
  compute_gates(th, gsh);
  phaseA_body(t, batch * 65536, wb, gsh, sre, sim, xre, xim, ws);
}

__global__ void __launch_bounds__(NT) pass2_k(const float* __restrict__ th,
                                              float2* __restrict__ ws) {
  __shared__ float gsh[256];
  __shared__ float sre[4096], sim[4096];
  int t = threadIdx.x;
  int blk = blockIdx.x, batch = blk >> 4, wb = blk & 15;
  compute_gates(th, gsh);
  __syncthreads();   // gsh ready before phaseB reads it
  phaseB_body(t, batch * 65536, wb, gsh, sre, sim, ws);
}

__global__ void __launch_bounds__(NT) pass3_k(const float* __restrict__ th,
                                              const float2* __restrict__ ws,
                                              float* __restrict__ out) {
  __shared__ float gsh[256];
  int t = threadIdx.x;
  int blk = blockIdx.x, batch = blk >> 3, g3 = blk & 7;
  compute_gates(th, gsh);
  __syncthreads();
  phaseC_body(t, batch * 65536, g3, gsh, ws, out);
}

// ====================== Cooperative fused kernel ======================

__device__ __forceinline__ void signal(unsigned* cnt) {
  __threadfence();
  __syncthreads();
  if (threadIdx.x == 0)
    __hip_atomic_fetch_add(cnt, 1u, __ATOMIC_RELEASE, __HIP_MEMORY_SCOPE_AGENT);
}

__device__ __forceinline__ void wait16(unsigned* cnt) {
  if (threadIdx.x == 0) {
    while (__hip_atomic_load(cnt, __ATOMIC_ACQUIRE, __HIP_MEMORY_SCOPE_AGENT) < 16u)
      __builtin_amdgcn_s_sleep(1);
  }
  __syncthreads();
  __threadfence();
}

__global__ void __launch_bounds__(NT, 2)
fused_k(const float* __restrict__ th,
        const float* __restrict__ xre, const float* __restrict__ xim,
        float2* __restrict__ ws, float* __restrict__ out,
        unsigned* __restrict__ cnt1, unsigned* __restrict__ cnt2) {
  __shared__ float gsh[256];
  __shared__ float sre[4096], sim[4096];
  int t = threadIdx.x;
  int blk = blockIdx.x;
  int batch = blk >> 4, wb = blk & 15;
  int bbase = batch * 65536;

  compute_gates(th, gsh);
  phaseA_body(t, bbase, wb, gsh, sre, sim, xre, xim, ws);
  signal(&cnt1[batch]);

  wait16(&cnt1[batch]);
  phaseB_body(t, bbase, wb, gsh, sre, sim, ws);
  signal(&cnt2[batch]);

  if (blk >= 256) return;
  int batch3 = blk >> 3, g3 = blk & 7;
  wait16(&cnt2[batch3]);
  phaseC_body(t, batch3 * 65536, g3, gsh, ws, out);
}

// ====================== Launcher ======================

extern "C" void kernel_launch(void* const* d_in, const int* in_sizes, int n_in,
                              void* d_out, int out_size, void* d_ws, size_t ws_size,
                              hipStream_t stream) {
  const float* th  = (const float*)d_in[0];   // (2,3,16)
  const float* xre = (const float*)d_in[1];   // (32,65536)
  const float* xim = (const float*)d_in[2];   // (32,65536)
  float* out = (float*)d_out;                 // (32,65536) fp32

  float2* amp = (float2*)d_ws;                              // 16 MB state
  unsigned* cnt1 = (unsigned*)((char*)d_ws + (16u << 20));  // 32+32 counters
  unsigned* cnt2 = cnt1 + 32;

  // Occupancy pre-check (pure query, capture-safe): need >= 2 blocks/CU so all
  // 512 blocks are co-resident (spin-sync deadlock-free).
  int maxBlk = 0;
  hipError_t qrc = hipOccupancyMaxActiveBlocksPerMultiprocessor(
      &maxBlk, (const void*)fused_k, NT, 0);
  bool try_coop = (qrc == hipSuccess && maxBlk >= 2);

  bool coop_ok = false;
  if (try_coop) {
    hipMemsetAsync((void*)cnt1, 0, 64 * sizeof(unsigned), stream);
    void* args[] = {(void*)&th, (void*)&xre, (void*)&xim,
                    (void*)&amp, (void*)&out, (void*)&cnt1, (void*)&cnt2};
    hipError_t rc = hipLaunchCooperativeKernel((const void*)fused_k, dim3(512),
                                               dim3(NT), args, 0, stream);
    coop_ok = (rc == hipSuccess);
  }

  if (!coop_ok) {
    // Verified R3 path.
    pass1_k<<<512, NT, 0, stream>>>(th, xre, xim, amp);
    pass2_k<<<512, NT, 0, stream>>>(th, amp);
    pass3_k<<<256, NT, 0, stream>>>(th, amp, out);
  }
}